// Round 6
// baseline (86.647 us; speedup 1.0000x reference)
//
#include <hip/hip_runtime.h>
#include <hip/hip_bf16.h>

#define N2 16384
#define D  128
#define SQC1 1.69864360258810896f         // sqrt(2*log2(e)), folded into zn
#define LN2  0.69314718055994530942f

typedef __bf16 bf16x8 __attribute__((ext_vector_type(8)));
typedef float  f32x4  __attribute__((ext_vector_type(4)));

#if __has_builtin(__builtin_amdgcn_exp2f)
#define EXP2(x) __builtin_amdgcn_exp2f(x)
#else
#define EXP2(x) exp2f(x)
#endif

__device__ __forceinline__ unsigned short f2bf(float f) {
    union { float f; unsigned u; } v; v.f = f;
    unsigned r = v.u + 0x7fffu + ((v.u >> 16) & 1u);
    return (unsigned short)(r >> 16);
}

// ---------- kernel 1: row L2-normalize -> bf16 sqrt(C1)*zn, + zero rowsum/out ----------
__global__ void k_norm(const float* __restrict__ z, unsigned short* __restrict__ zn,
                       float* __restrict__ rowsum, float* __restrict__ out) {
    if (blockIdx.x < 64) rowsum[blockIdx.x * 256 + threadIdx.x] = 0.f;
    if (blockIdx.x == 64 && threadIdx.x == 0) out[0] = 0.f;
    int row  = blockIdx.x * 4 + (threadIdx.x >> 6);
    int lane = threadIdx.x & 63;
    const float2 v = ((const float2*)(z + (size_t)row * D))[lane];
    float ss = v.x * v.x + v.y * v.y;
    #pragma unroll
    for (int m = 1; m < 64; m <<= 1) ss += __shfl_xor(ss, m);
    float inv = SQC1 / fmaxf(sqrtf(ss), 1e-12f);
    ushort2 o; o.x = f2bf(v.x * inv); o.y = f2bf(v.y * inv);
    ((ushort2*)(zn + (size_t)row * D))[lane] = o;
}

// ---------- kernel 2: barrier-free, LDS-free symmetric sim + exp sums ----------
// 2048 independent wave-jobs. Job = (ti: 64-row stripe [0,256), chunk [0,8)).
// Wave holds A(ti) in regs; sweeps s in [16c, 16c+16) (chunk 7 adds s=128 when
// ti<128); B-subtile (jt=(ti+s)&255, 64x128) loaded global->reg each step
// (L2-resident: zn is 4 MB = one XCD L2). s=0: diagonal, mask li==lj, row
// sums only. s>0: row sums (regs) + col sums (atomics, by symmetry).
__global__ __launch_bounds__(256, 2)
void k_sim(const unsigned short* __restrict__ zn, float* __restrict__ rowsum) {
    const int wid = threadIdx.x >> 6, lane = threadIdx.x & 63;
    const int job = blockIdx.x * 4 + wid;            // 0..2047
    const int ti = job >> 3;                         // 64-row stripe
    const int chunk = job & 7;
    const int sLo = chunk * 16;
    const int nt = (chunk == 7 && ti < 128) ? 17 : 16;
    const int l16 = lane & 15, lg = lane >> 4;
    const char* znb = (const char*)zn;
    const f32x4 ZERO = {0.f, 0.f, 0.f, 0.f};

    // per-lane base byte offset within a 64x256B stripe (row=l16, kchunk=lg)
    const int laneoff = l16 * 256 + lg * 16;

    // A fragments: 64 rows x 128 k -> 16 x bf16x8 (one L2 read, reused nt steps)
    bf16x8 af[4][4];                                 // [kk][m]
    {
        const char* ab = znb + (size_t)ti * 16384 + laneoff;
        #pragma unroll
        for (int kk = 0; kk < 4; ++kk)
            #pragma unroll
            for (int m = 0; m < 4; ++m)
                af[kk][m] = *(const bf16x8*)(ab + m * 4096 + kk * 64);
    }

    float rs[4][4];
    #pragma unroll
    for (int m = 0; m < 4; ++m)
        #pragma unroll
        for (int r = 0; r < 4; ++r) rs[m][r] = 0.f;

    for (int t = 0; t < nt; ++t) {
        const int s  = sLo + t;
        const int jt = (ti + s) & 255;
        const char* bb = znb + (size_t)jt * 16384 + laneoff;

        bf16x8 bfr[4][4];                            // [kk][n]
        #pragma unroll
        for (int kk = 0; kk < 4; ++kk)
            #pragma unroll
            for (int n = 0; n < 4; ++n)
                bfr[kk][n] = *(const bf16x8*)(bb + n * 4096 + kk * 64);

        f32x4 acc[4][4];
        __builtin_amdgcn_s_setprio(1);
        #pragma unroll
        for (int m = 0; m < 4; ++m)
            #pragma unroll
            for (int n = 0; n < 4; ++n)
                acc[m][n] = __builtin_amdgcn_mfma_f32_16x16x32_bf16(af[0][m], bfr[0][n], ZERO, 0, 0, 0);
        #pragma unroll
        for (int kk = 1; kk < 4; ++kk)
            #pragma unroll
            for (int m = 0; m < 4; ++m)
                #pragma unroll
                for (int n = 0; n < 4; ++n)
                    acc[m][n] = __builtin_amdgcn_mfma_f32_16x16x32_bf16(af[kk][m], bfr[kk][n], acc[m][n], 0, 0, 0);
        __builtin_amdgcn_s_setprio(0);

        // epilogue: e = exp2(acc) = exp(sim)
        if (s == 0) {
            // diagonal subtile: mask self-sim, row sums only
            #pragma unroll
            for (int m = 0; m < 4; ++m)
                #pragma unroll
                for (int r = 0; r < 4; ++r) {
                    int li = m * 16 + lg * 4 + r;
                    float a = 0.f;
                    #pragma unroll
                    for (int n = 0; n < 4; ++n) {
                        int lj = n * 16 + l16;
                        float e = EXP2(acc[m][n][r]);
                        a += (li == lj) ? 0.f : e;
                    }
                    rs[m][r] += a;
                }
        } else {
            float cs[4] = {0.f, 0.f, 0.f, 0.f};
            #pragma unroll
            for (int m = 0; m < 4; ++m)
                #pragma unroll
                for (int r = 0; r < 4; ++r) {
                    float a = 0.f;
                    #pragma unroll
                    for (int n = 0; n < 4; ++n) {
                        float e = EXP2(acc[m][n][r]);
                        a += e;
                        cs[n] += e;
                    }
                    rs[m][r] += a;
                }
            // column sums: reduce over the 4 lg row-groups, one atomic per col
            #pragma unroll
            for (int n = 0; n < 4; ++n) {
                float v = cs[n];
                v += __shfl_xor(v, 16);
                v += __shfl_xor(v, 32);
                if (lg == 0)
                    atomicAdd(&rowsum[jt * 64 + n * 16 + l16], v);
            }
        }
    }

    // row-sum flush: reduce across the 16 column-lanes, one atomic per row
    #pragma unroll
    for (int m = 0; m < 4; ++m)
        #pragma unroll
        for (int r = 0; r < 4; ++r) {
            float v = rs[m][r];
            v += __shfl_xor(v, 1);
            v += __shfl_xor(v, 2);
            v += __shfl_xor(v, 4);
            v += __shfl_xor(v, 8);
            if (l16 == 0)
                atomicAdd(&rowsum[ti * 64 + m * 16 + lg * 4 + r], v);
        }
}

// ---------- kernel 3: fused loss + mean ----------
// mean loss = (1/N2) * [ sum_i ln(rowsum_i) - ln2 * sum_{i,k} zn'[i][k]*zn'[i^1][k] ]
__global__ void k_loss_reduce(const unsigned short* __restrict__ zn,
                              const float* __restrict__ rowsum,
                              float* __restrict__ out) {
    const int tid = threadIdx.x + blockIdx.x * 256;   // 64 blocks x 256
    float p = 0.f;
    const bf16x8* v8 = (const bf16x8*)zn;
    for (int v = tid; v < N2 * D / 8; v += 64 * 256) {
        bf16x8 a = v8[v];
        bf16x8 b = v8[v ^ 16];                        // row i^1, same k-slice
        #pragma unroll
        for (int e = 0; e < 8; ++e) p += (float)a[e] * (float)b[e];
    }
    float part = logf(rowsum[tid]) - LN2 * p;         // exactly one row per thread

    __shared__ float sm[4];
    #pragma unroll
    for (int m = 1; m < 64; m <<= 1) part += __shfl_xor(part, m);
    if ((threadIdx.x & 63) == 0) sm[threadIdx.x >> 6] = part;
    __syncthreads();
    if (threadIdx.x == 0)
        atomicAdd(out, (sm[0] + sm[1] + sm[2] + sm[3]) * (1.0f / (float)N2));
}

extern "C" void kernel_launch(void* const* d_in, const int* in_sizes, int n_in,
                              void* d_out, int out_size, void* d_ws, size_t ws_size,
                              hipStream_t stream) {
    const float* z = (const float*)d_in[0];
    float* out = (float*)d_out;

    unsigned short* zn = (unsigned short*)d_ws;                       // 4 MiB
    float* rowsum = (float*)((char*)d_ws + (size_t)N2 * D * 2);       // 64 KiB

    k_norm<<<N2 / 4, 256, 0, stream>>>(z, zn, rowsum, out);
    k_sim<<<512, 256, 0, stream>>>(zn, rowsum);
    k_loss_reduce<<<64, 256, 0, stream>>>(zn, rowsum, out);
}

// Round 7
// 69.197 us; speedup vs baseline: 1.2522x; 1.2522x over previous
//
#include <hip/hip_runtime.h>
#include <hip/hip_bf16.h>

#define N2 16384
#define D  128
#define PANEL 32768                       // bytes per 128x128 bf16 panel
#define SQC1 1.69864360258810896f         // sqrt(2*log2(e)), folded into zn
#define LN2  0.69314718055994530942f

typedef __bf16 bf16x8 __attribute__((ext_vector_type(8)));
typedef float  f32x4  __attribute__((ext_vector_type(4)));

#if __has_builtin(__builtin_amdgcn_exp2f)
#define EXP2(x) __builtin_amdgcn_exp2f(x)
#else
#define EXP2(x) exp2f(x)
#endif

__device__ __forceinline__ unsigned short f2bf(float f) {
    union { float f; unsigned u; } v; v.f = f;
    unsigned r = v.u + 0x7fffu + ((v.u >> 16) & 1u);
    return (unsigned short)(r >> 16);
}

// stage one 32KB panel global->LDS via global_load_lds width=16.
// LDS dest linear; XOR swizzle on the GLOBAL source (involution); reads
// use byte ^ ((row&7)<<4). (rule #21)
__device__ __forceinline__ void stage_panel(const char* __restrict__ g,
                                            char* lds, int tid) {
    const int wid = tid >> 6, lane = tid & 63;
    #pragma unroll
    for (int i = 0; i < 8; ++i) {
        int off = (wid << 13) + (i << 10) + (lane << 4);
        int src = off ^ (((off >> 8) & 7) << 4);
        __builtin_amdgcn_global_load_lds(
            (const __attribute__((address_space(1))) unsigned*)(g + src),
            (__attribute__((address_space(3))) unsigned*)(lds + (wid << 13) + (i << 10)),
            16, 0, 0);
    }
}

// ---------- kernel 1: row L2-normalize -> bf16 sqrt(C1)*zn, + zero rowsum/out ----------
__global__ void k_norm(const float* __restrict__ z, unsigned short* __restrict__ zn,
                       float* __restrict__ rowsum, float* __restrict__ out) {
    if (blockIdx.x < 64) rowsum[blockIdx.x * 256 + threadIdx.x] = 0.f;
    if (blockIdx.x == 64 && threadIdx.x == 0) out[0] = 0.f;
    int row  = blockIdx.x * 4 + (threadIdx.x >> 6);
    int lane = threadIdx.x & 63;
    const float2 v = ((const float2*)(z + (size_t)row * D))[lane];
    float ss = v.x * v.x + v.y * v.y;
    #pragma unroll
    for (int m = 1; m < 64; m <<= 1) ss += __shfl_xor(ss, m);
    float inv = SQC1 / fmaxf(sqrtf(ss), 1e-12f);
    ushort2 o; o.x = f2bf(v.x * inv); o.y = f2bf(v.y * inv);
    ((ushort2*)(zn + (size_t)row * D))[lane] = o;
}

// ---------- kernel 2: symmetric fused sim GEMM + exp row/col sums ----------
// block (c, ti): s in [16c, 16c+16) (+s=64 for c==3, ti<64). jt=(ti+s)&127.
// A(ti) in regs (staged once); B panels double-buffered in 2x32KB.
// ONE barrier per tile; compute window {ds_read|MFMA|epilogue} is sync-free
// so waves de-phase and epilogue VALU overlaps other waves' MFMA.
// Column sums go to LDS (ds_add), flushed once at the end -> no global
// atomics inside the loop -> vmcnt(0) drains only the 8 stage loads.
__global__ __launch_bounds__(256, 2)
void k_sim(const unsigned short* __restrict__ zn, float* __restrict__ rowsum) {
    __shared__ char ls[2 * PANEL];        // 64KB: B double-buffer (A prologue via ls0)
    __shared__ float colbuf[17 * 128];    // per-block column-sum accumulator
    char* ls0 = ls;
    char* ls1 = ls + PANEL;

    const int tileI = blockIdx.y;
    const int c = blockIdx.x;
    const int sLo = c * 16;
    const int nt = (c == 3 && tileI < 64) ? 17 : 16;

    const int tid  = threadIdx.x;
    const int lane = tid & 63, wid = tid >> 6;
    const int wr = wid >> 1, wc = wid & 1;          // 2x2 waves: 64x64 each
    const int l16 = lane & 15, lg = lane >> 4;
    const char* znb = (const char*)zn;
    const f32x4 ZERO = {0.f, 0.f, 0.f, 0.f};

    #pragma unroll
    for (int u = tid; u < 17 * 128; u += 256) colbuf[u] = 0.f;

    // prologue: stage A(ti) -> ls0, pull A fragments to registers
    stage_panel(znb + (size_t)tileI * PANEL, ls0, tid);
    asm volatile("s_waitcnt vmcnt(0)" ::: "memory");
    __builtin_amdgcn_s_barrier();

    bf16x8 af[4][4];                                   // [kk][m]
    #pragma unroll
    for (int kk = 0; kk < 4; ++kk)
        #pragma unroll
        for (int m = 0; m < 4; ++m) {
            int row = wr * 64 + m * 16 + l16;
            int d = row * 256 + kk * 64 + lg * 16;
            af[kk][m] = *(const bf16x8*)(ls0 + (d ^ ((row & 7) << 4)));
        }
    asm volatile("s_waitcnt lgkmcnt(0)" ::: "memory");
    __builtin_amdgcn_s_barrier();                      // ls0 free for B

    // first B panel -> ls0 (rbuf for t=0)
    stage_panel(znb + (size_t)((tileI + sLo) & 127) * PANEL, ls0, tid);

    float rs[4][4];
    #pragma unroll
    for (int m = 0; m < 4; ++m)
        #pragma unroll
        for (int r = 0; r < 4; ++r) rs[m][r] = 0.f;

    for (int t = 0; t < nt; ++t) {
        const int s = sLo + t;

        // --- single sync point per tile ---
        asm volatile("s_waitcnt vmcnt(0)" ::: "memory");   // B(t) writes (mine) done
        __builtin_amdgcn_s_barrier();                      // all writes visible; all prev reads done

        char* rbuf = (t & 1) ? ls1 : ls0;
        char* sbuf = (t & 1) ? ls0 : ls1;
        if (t + 1 < nt)
            stage_panel(znb + (size_t)((tileI + s + 1) & 127) * PANEL, sbuf, tid);

        // compute window: no barriers. Compiler handles ds_read->MFMA waits.
        bf16x8 bfr[4][4];                              // [kk][n]
        #pragma unroll
        for (int kk = 0; kk < 4; ++kk)
            #pragma unroll
            for (int n = 0; n < 4; ++n) {
                int row = wc * 64 + n * 16 + l16;
                int d = row * 256 + kk * 64 + lg * 16;
                bfr[kk][n] = *(const bf16x8*)(rbuf + (d ^ ((row & 7) << 4)));
            }

        f32x4 acc[4][4];
        __builtin_amdgcn_s_setprio(1);
        #pragma unroll
        for (int m = 0; m < 4; ++m)
            #pragma unroll
            for (int n = 0; n < 4; ++n)
                acc[m][n] = __builtin_amdgcn_mfma_f32_16x16x32_bf16(af[0][m], bfr[0][n], ZERO, 0, 0, 0);
        #pragma unroll
        for (int kk = 1; kk < 4; ++kk)
            #pragma unroll
            for (int m = 0; m < 4; ++m)
                #pragma unroll
                for (int n = 0; n < 4; ++n)
                    acc[m][n] = __builtin_amdgcn_mfma_f32_16x16x32_bf16(af[kk][m], bfr[kk][n], acc[m][n], 0, 0, 0);
        __builtin_amdgcn_s_setprio(0);

        // epilogue: e = exp2(acc) = exp(sim)
        if (s == 0) {
            // diagonal tile: mask self-sim, row sums only
            #pragma unroll
            for (int m = 0; m < 4; ++m)
                #pragma unroll
                for (int r = 0; r < 4; ++r) {
                    int li = wr * 64 + m * 16 + lg * 4 + r;
                    float a = 0.f;
                    #pragma unroll
                    for (int n = 0; n < 4; ++n) {
                        int lj = wc * 64 + n * 16 + l16;
                        float e = EXP2(acc[m][n][r]);
                        a += (li == lj) ? 0.f : e;
                    }
                    rs[m][r] += a;
                }
        } else {
            float cs[4] = {0.f, 0.f, 0.f, 0.f};
            #pragma unroll
            for (int m = 0; m < 4; ++m)
                #pragma unroll
                for (int r = 0; r < 4; ++r) {
                    float a = 0.f;
                    #pragma unroll
                    for (int n = 0; n < 4; ++n) {
                        float e = EXP2(acc[m][n][r]);
                        a += e;
                        cs[n] += e;
                    }
                    rs[m][r] += a;
                }
            // column sums -> LDS colbuf (reduce over lg groups, 16 lanes add)
            #pragma unroll
            for (int n = 0; n < 4; ++n) {
                float v = cs[n];
                v += __shfl_xor(v, 16);
                v += __shfl_xor(v, 32);
                if (lg == 0)
                    atomicAdd(&colbuf[t * 128 + wc * 64 + n * 16 + l16], v);
            }
        }
    }

    // row-sum flush: reduce across 16 column-lanes, one global atomic per row
    #pragma unroll
    for (int m = 0; m < 4; ++m)
        #pragma unroll
        for (int r = 0; r < 4; ++r) {
            float v = rs[m][r];
            v += __shfl_xor(v, 1);
            v += __shfl_xor(v, 2);
            v += __shfl_xor(v, 4);
            v += __shfl_xor(v, 8);
            if (l16 == 0)
                atomicAdd(&rowsum[tileI * 128 + wr * 64 + m * 16 + lg * 4 + r], v);
        }

    // column-sum flush: LDS -> global, once per block
    asm volatile("s_waitcnt lgkmcnt(0)" ::: "memory");     // ds_adds drained
    __builtin_amdgcn_s_barrier();
    for (int u = tid; u < nt * 128; u += 256) {
        int t = u >> 7, col = u & 127;
        int jt = (tileI + sLo + t) & 127;
        float v = colbuf[u];
        if (v != 0.f)
            atomicAdd(&rowsum[jt * 128 + col], v);
    }
}

// ---------- kernel 3: fused loss + mean ----------
// mean loss = (1/N2) * [ sum_i ln(rowsum_i) - ln2 * sum_{i,k} zn'[i][k]*zn'[i^1][k] ]
__global__ void k_loss_reduce(const unsigned short* __restrict__ zn,
                              const float* __restrict__ rowsum,
                              float* __restrict__ out) {
    const int tid = threadIdx.x + blockIdx.x * 256;   // 64 blocks x 256
    float p = 0.f;
    const bf16x8* v8 = (const bf16x8*)zn;
    for (int v = tid; v < N2 * D / 8; v += 64 * 256) {
        bf16x8 a = v8[v];
        bf16x8 b = v8[v ^ 16];                        // row i^1, same k-slice
        #pragma unroll
        for (int e = 0; e < 8; ++e) p += (float)a[e] * (float)b[e];
    }
    float part = logf(rowsum[tid]) - LN2 * p;         // exactly one row per thread

    __shared__ float sm[4];
    #pragma unroll
    for (int m = 1; m < 64; m <<= 1) part += __shfl_xor(part, m);
    if ((threadIdx.x & 63) == 0) sm[threadIdx.x >> 6] = part;
    __syncthreads();
    if (threadIdx.x == 0)
        atomicAdd(out, (sm[0] + sm[1] + sm[2] + sm[3]) * (1.0f / (float)N2));
}

extern "C" void kernel_launch(void* const* d_in, const int* in_sizes, int n_in,
                              void* d_out, int out_size, void* d_ws, size_t ws_size,
                              hipStream_t stream) {
    const float* z = (const float*)d_in[0];
    float* out = (float*)d_out;

    unsigned short* zn = (unsigned short*)d_ws;                       // 4 MiB
    float* rowsum = (float*)((char*)d_ws + (size_t)N2 * D * 2);       // 64 KiB

    k_norm<<<N2 / 4, 256, 0, stream>>>(z, zn, rowsum, out);
    dim3 grid(4, 128);                                                // s-chunks x i-tiles
    k_sim<<<grid, 256, 0, stream>>>(zn, rowsum);
    k_loss_reduce<<<64, 256, 0, stream>>>(zn, rowsum, out);
}